// Round 12
// baseline (275.541 us; speedup 1.0000x reference)
//
#include <hip/hip_runtime.h>
#include <cmath>

#define Bdim 8
#define Cdim 768
#define Kdim 256
#define Ndim 4096
#define NT 64      // tokens per block in kernel 1
#define KC2 32     // C-chunk per MFMA stage (3-buffered)
#define NCH (Cdim / KC2)   // 24
#define CB2 4      // c-rows per block in kernel 2
#define NCOPY 4    // replicated LDS accumulators in kernel 2

typedef __bf16 bf16x8 __attribute__((ext_vector_type(8)));
typedef short  s16x8  __attribute__((ext_vector_type(8)));
typedef float  f32x4  __attribute__((ext_vector_type(4)));
union U8 { s16x8 s; bf16x8 b; };

// direct global->LDS DMA, 16B per lane, wave-uniform LDS base
typedef __attribute__((address_space(1))) const unsigned int g_u32;
typedef __attribute__((address_space(3))) unsigned int l_u32;
__device__ __forceinline__ void gload16(const void* g, void* l) {
    __builtin_amdgcn_global_load_lds((g_u32*)g, (l_u32*)l, 16, 0, 0);
}

// native LDS float atomic add (fire-and-forget ds_add_f32), NO memory
// clobber: a "memory" clobber pins global loads below each add and
// re-serializes the load stream (r11 lesson: VGPR=28, loads 1-deep).
// Volatile asm still orders against barriers and other volatile asm.
// Caller MUST drain with an explicit s_waitcnt lgkmcnt(0) before reading.
__device__ __forceinline__ void lds_fadd_nc(float* p, float v) {
    auto lp = (__attribute__((address_space(3))) float*)p;
    asm volatile("ds_add_f32 %0, %1"
                 :: "v"((unsigned)(unsigned long long)lp), "v"(v));
}

// three-level bf16 split, RNE at each level; v = h + m + l + eps, |eps| <= 2^-27 |v|
__device__ __forceinline__ void split3(float v, short& h, short& m, short& l) {
    unsigned u = __float_as_uint(v);
    unsigned th = u + 0x7FFFu + ((u >> 16) & 1u);
    h = (short)(th >> 16);
    float r1 = v - __uint_as_float(th & 0xFFFF0000u);      // exact
    unsigned u1 = __float_as_uint(r1);
    unsigned tm = u1 + 0x7FFFu + ((u1 >> 16) & 1u);
    m = (short)(tm >> 16);
    float r2 = r1 - __uint_as_float(tm & 0xFFFF0000u);     // exact
    unsigned u2 = __float_as_uint(r2);
    unsigned tl = u2 + 0x7FFFu + ((u2 >> 16) & 1u);
    l = (short)(tl >> 16);
}

// Prep: per batch b — centroid inverse norms (fp32, exact) + zero cnt.
__global__ __launch_bounds__(256) void prep_kernel(
    const float* __restrict__ cents, float* __restrict__ invc, int* __restrict__ cnt)
{
    __shared__ float red[4][Kdim];
    const int tid = threadIdx.x;
    const int b = blockIdx.x;
    const float* cb = cents + (size_t)b * Cdim * Kdim;
    const int q = tid & 63, g = tid >> 6;
    float4 ss = make_float4(0.f, 0.f, 0.f, 0.f);
    for (int r = g; r < Cdim; r += 4) {
        float4 v = *(const float4*)(cb + (size_t)r * Kdim + q * 4);
        ss.x = fmaf(v.x, v.x, ss.x); ss.y = fmaf(v.y, v.y, ss.y);
        ss.z = fmaf(v.z, v.z, ss.z); ss.w = fmaf(v.w, v.w, ss.w);
    }
    *(float4*)&red[g][q * 4] = ss;
    __syncthreads();
    float s = red[0][tid] + red[1][tid] + red[2][tid] + red[3][tid];
    invc[b * Kdim + tid] = 1.f / fmaxf(sqrtf(s), 1e-12f);
    cnt[b * Kdim + tid] = 0;
}

// Cvt: centroids -> split-3 bf16 planes in MFMA-fragment layout
// plane[(b*96 + c/8)*256 + k][8]: 8 consecutive c per 16B record.
__global__ __launch_bounds__(256) void cvt_kernel(
    const float* __restrict__ cents, short* __restrict__ centH,
    short* __restrict__ centM, short* __restrict__ centL)
{
    const int k = threadIdx.x;
    const int bc = blockIdx.x;                    // b*96 + c8
    const float* src = cents + ((size_t)(bc / 96) * Cdim + (size_t)(bc % 96) * 8) * Kdim + k;
    s16x8 H, M, L;
    #pragma unroll
    for (int e = 0; e < 8; ++e) {
        short h, m, l;
        split3(src[(size_t)e * Kdim], h, m, l);   // coalesced across lanes (k)
        H[e] = h; M[e] = m; L[e] = l;
    }
    ((s16x8*)centH)[(size_t)bc * 256 + k] = H;    // 16B coalesced stores
    ((s16x8*)centM)[(size_t)bc * 256 + k] = M;
    ((s16x8*)centL)[(size_t)bc * 256 + k] = L;
}

// Kernel 1: per (b, n-tile of 64): cos via split-3 bf16 MFMA, 6 passes
// (hh, hm, mh, hl, lh, mm) into ONE accumulator (noise ~1.5e-8 cos, safe).
// __launch_bounds__(256,2): 2 waves/SIMD is the grid cap anyway; this frees
// the full ~256-VGPR budget so acc + 24 fragments stay live (no remat).
__global__ __launch_bounds__(256, 2) void sim_mfma_kernel(
    const float* __restrict__ x,        // (B,C,N) fp32
    const short* __restrict__ centH,
    const short* __restrict__ centM,
    const short* __restrict__ centL,
    const float* __restrict__ alpha_p,
    const float* __restrict__ beta_p,
    const float* __restrict__ invc,     // (B,K) fp32
    float* __restrict__ simOut,         // (B,K,N), pre-zeroed
    float* __restrict__ wArr,
    int*   __restrict__ kArr,
    int*   __restrict__ cnt)
{
    __shared__ __align__(16) float sxf[3][KC2][NT];  // 24 KB fp32 x chunks
    __shared__ float invcS[Kdim];
    __shared__ float px[4][NT];
    __shared__ float invxS[NT];
    __shared__ float bwv[4][NT];
    __shared__ int   bwk[4][NT];

    const int tid  = threadIdx.x;
    const int lane = tid & 63;
    const int w    = tid >> 6;          // wave id: k-range [w*64, w*64+64)
    const int q    = lane >> 4;         // 0..3
    const int c15  = lane & 15;
    const int b    = blockIdx.x >> 6;
    const int n0   = (blockIdx.x & 63) * NT;
    const float* xb = x + (size_t)b * Cdim * Ndim;

    invcS[tid] = invc[b * Kdim + tid];
    const float alpha = alpha_p[0];
    const float beta  = beta_p[0];

    f32x4 acc[4][4];
    #pragma unroll
    for (int i = 0; i < 4; ++i)
        #pragma unroll
        for (int j = 0; j < 4; ++j) acc[i][j] = (f32x4){0.f, 0.f, 0.f, 0.f};

    float xn2p = 0.f;

    // exactly 2 DMA (vmcnt) ops per wave per STAGE
    #define STAGE(t_) do {                                                    \
        const int bf_ = (t_) % 3; const int c0_ = (t_) * KC2;                 \
        _Pragma("unroll")                                                     \
        for (int i_ = 0; i_ < 2; ++i_)                                        \
            gload16(xb + (size_t)(c0_ + w * 8 + i_ * 4 + q) * Ndim            \
                       + n0 + c15 * 4,                                        \
                    &sxf[bf_][w * 8 + i_ * 4][0]);                            \
    } while (0)

    STAGE(0);
    STAGE(1);

    const s16x8* cHb = (const s16x8*)centH + ((size_t)b * 96) * 256;
    const s16x8* cMb = (const s16x8*)centM + ((size_t)b * 96) * 256;
    const s16x8* cLb = (const s16x8*)centL + ((size_t)b * 96) * 256;

    for (int t = 0; t < NCH; ++t) {
        // retire everything except STAGE(t+1)'s 2 newest; chunk t ready
        asm volatile("s_waitcnt vmcnt(2)" ::: "memory");
        __builtin_amdgcn_s_barrier();
        __builtin_amdgcn_sched_barrier(0);

        const int cur = t % 3;

        // A fragments (12 16B loads, L2/L3-resident planes), before next STAGE
        U8 aH[4], aM[4], aL[4];
        {
            const size_t rowb = ((size_t)(t * 4 + q)) * 256 + w * 64 + c15;
            #pragma unroll
            for (int kf = 0; kf < 4; ++kf) {
                aH[kf].s = cHb[rowb + kf * 16];
                aM[kf].s = cMb[rowb + kf * 16];
                aL[kf].s = cLb[rowb + kf * 16];
            }
        }
        if (t + 2 < NCH) STAGE(t + 2);

        // x-norm partials (rows w*8..w*8+7, col = lane)
        #pragma unroll
        for (int r = 0; r < 8; ++r) {
            float v = sxf[cur][w * 8 + r][lane];
            xn2p = fmaf(v, v, xn2p);
        }

        // B fragments: split fp32 tile -> h/m/l bf16 in-register
        U8 bH[4], bM[4], bL[4];
        #pragma unroll
        for (int nf = 0; nf < 4; ++nf) {
            #pragma unroll
            for (int e = 0; e < 8; ++e) {
                short h, m, l;
                split3(sxf[cur][q * 8 + e][nf * 16 + c15], h, m, l);
                bH[nf].s[e] = h; bM[nf].s[e] = m; bL[nf].s[e] = l;
            }
        }

        // 6 passes x 16 fragment-MFMAs, pass-major, single accumulator
        #pragma unroll
        for (int kf = 0; kf < 4; ++kf)
            #pragma unroll
            for (int nf = 0; nf < 4; ++nf)
                acc[kf][nf] = __builtin_amdgcn_mfma_f32_16x16x32_bf16(
                    aH[kf].b, bH[nf].b, acc[kf][nf], 0, 0, 0);
        #pragma unroll
        for (int kf = 0; kf < 4; ++kf)
            #pragma unroll
            for (int nf = 0; nf < 4; ++nf)
                acc[kf][nf] = __builtin_amdgcn_mfma_f32_16x16x32_bf16(
                    aH[kf].b, bM[nf].b, acc[kf][nf], 0, 0, 0);
        #pragma unroll
        for (int kf = 0; kf < 4; ++kf)
            #pragma unroll
            for (int nf = 0; nf < 4; ++nf)
                acc[kf][nf] = __builtin_amdgcn_mfma_f32_16x16x32_bf16(
                    aM[kf].b, bH[nf].b, acc[kf][nf], 0, 0, 0);
        #pragma unroll
        for (int kf = 0; kf < 4; ++kf)
            #pragma unroll
            for (int nf = 0; nf < 4; ++nf)
                acc[kf][nf] = __builtin_amdgcn_mfma_f32_16x16x32_bf16(
                    aH[kf].b, bL[nf].b, acc[kf][nf], 0, 0, 0);
        #pragma unroll
        for (int kf = 0; kf < 4; ++kf)
            #pragma unroll
            for (int nf = 0; nf < 4; ++nf)
                acc[kf][nf] = __builtin_amdgcn_mfma_f32_16x16x32_bf16(
                    aL[kf].b, bH[nf].b, acc[kf][nf], 0, 0, 0);
        #pragma unroll
        for (int kf = 0; kf < 4; ++kf)
            #pragma unroll
            for (int nf = 0; nf < 4; ++nf)
                acc[kf][nf] = __builtin_amdgcn_mfma_f32_16x16x32_bf16(
                    aM[kf].b, bM[nf].b, acc[kf][nf], 0, 0, 0);
    }
    #undef STAGE

    __syncthreads();
    px[w][lane] = xn2p;
    __syncthreads();
    if (tid < NT) {
        float s = px[0][tid] + px[1][tid] + px[2][tid] + px[3][tid];
        invxS[tid] = 1.f / fmaxf(sqrtf(s), 1e-12f);
    }
    __syncthreads();

    // epilogue: cos -> sigmoid -> argmax (first-win = min-k on ties)
    // D layout: row(k_local) = q*4 + reg, col(n) = c15
    #pragma unroll
    for (int nf = 0; nf < 4; ++nf) {
        const float ivx = invxS[nf * 16 + c15];
        float best = -1.f; int bk = 0;
        #pragma unroll
        for (int kf = 0; kf < 4; ++kf) {
            float4 ic = *(const float4*)&invcS[w * 64 + kf * 16 + q * 4];
            #pragma unroll
            for (int r = 0; r < 4; ++r) {
                float cosv = acc[kf][nf][r] * ((const float*)&ic)[r] * ivx;
                float s = 1.f / (1.f + expf(-(beta + alpha * cosv)));
                int k = w * 64 + kf * 16 + q * 4 + r;
                if (s > best) { best = s; bk = k; }   // ascending k scan
            }
        }
        // reduce across q-groups (lanes l, l^16, l^32, l^48 share n)
        #pragma unroll
        for (int off = 16; off < 64; off <<= 1) {
            float ov = __shfl_xor(best, off);
            int   ok = __shfl_xor(bk, off);
            if (ov > best || (ov == best && ok < bk)) { best = ov; bk = ok; }
        }
        if (q == 0) { bwv[w][nf * 16 + c15] = best; bwk[w][nf * 16 + c15] = bk; }
    }
    __syncthreads();
    if (tid < NT) {
        float best = -1.f; int bk = 0;
        #pragma unroll
        for (int g = 0; g < 4; ++g) {    // ascending waves = ascending k
            float v = bwv[g][tid];
            if (v > best) { best = v; bk = bwk[g][tid]; }
        }
        int gn = b * Ndim + n0 + tid;
        wArr[gn] = best;
        kArr[gn] = bk;
        simOut[((size_t)(b * Kdim + bk)) * Ndim + n0 + tid] = best;
        atomicAdd(&cnt[b * Kdim + bk], 1);
    }
}

// Kernel 2: per (b, 4 c-rows): Phase 1 issues ALL 24 16B loads as one pure
// batch (x is L3-resident after k1); Phase 2 scatters via clobber-free
// ds_add_f32; explicit lgkmcnt drain before the barrier. Fused epilogue.
__global__ __launch_bounds__(256, 4) void agg_kernel(
    const float* __restrict__ x, const float* __restrict__ cents,
    const float* __restrict__ wArr, const int* __restrict__ kArr,
    const int* __restrict__ cnt, float* __restrict__ hyp)
{
    __shared__ float accs[NCOPY][CB2][Kdim + 1];
    const int tid = threadIdx.x;
    const int b  = blockIdx.x / (Cdim / CB2);
    const int c0 = (blockIdx.x % (Cdim / CB2)) * CB2;
    const int cp = tid & 3;
    const float* xb = x + ((size_t)b * Cdim + c0) * Ndim;

    // Phase 1: issue ALL global loads (pure straight-line; nothing pins them)
    int4 kv[4]; float4 w4[4]; float4 xv[4][CB2];
    #pragma unroll
    for (int i = 0; i < 4; ++i) {
        const int n = (tid + i * 256) * 4;
        kv[i] = *(const int4*)&kArr[b * Ndim + n];
        w4[i] = *(const float4*)&wArr[b * Ndim + n];
        #pragma unroll
        for (int r = 0; r < CB2; ++r)
            xv[i][r] = *(const float4*)&xb[(size_t)r * Ndim + n];
    }

    // accs zero-init hides under the load latency (LDS-only stores)
    for (int i = tid; i < NCOPY * CB2 * (Kdim + 1); i += 256) ((float*)accs)[i] = 0.f;
    __syncthreads();
    __builtin_amdgcn_sched_barrier(0);   // loads stay above, scatter below

    // Phase 2: fire-and-forget ds_add_f32 in load-retirement order
    #pragma unroll
    for (int i = 0; i < 4; ++i)
        #pragma unroll
        for (int r = 0; r < CB2; ++r) {
            lds_fadd_nc(&accs[cp][r][kv[i].x], w4[i].x * xv[i][r].x);
            lds_fadd_nc(&accs[cp][r][kv[i].y], w4[i].y * xv[i][r].y);
            lds_fadd_nc(&accs[cp][r][kv[i].z], w4[i].z * xv[i][r].z);
            lds_fadd_nc(&accs[cp][r][kv[i].w], w4[i].w * xv[i][r].w);
        }

    // compiler doesn't track the asm ds_adds -> drain them ourselves
    asm volatile("s_waitcnt lgkmcnt(0)" ::: "memory");
    __builtin_amdgcn_sched_barrier(0);
    __syncthreads();

    // fused epilogue: hyp[b][k][c0+cl] = (sum copies + ct)/(cnt+1)
    const int cl = tid & 3;
    #pragma unroll
    for (int it = 0; it < 4; ++it) {
        int k = (tid >> 2) + it * 64;
        float s = accs[0][cl][k] + accs[1][cl][k] + accs[2][cl][k] + accs[3][cl][k];
        float num = s + cents[((size_t)b * Cdim + c0 + cl) * Kdim + k];
        hyp[((size_t)(b * Kdim + k)) * Cdim + c0 + cl] = num / (float)(cnt[b * Kdim + k] + 1);
    }
}

extern "C" void kernel_launch(void* const* d_in, const int* in_sizes, int n_in,
                              void* d_out, int out_size, void* d_ws, size_t ws_size,
                              hipStream_t stream)
{
    const float* x     = (const float*)d_in[0];
    const float* cents = (const float*)d_in[1];
    const float* alpha = (const float*)d_in[2];
    const float* beta  = (const float*)d_in[3];

    float* hyp    = (float*)d_out;                                    // (B,K,C)
    float* simOut = (float*)d_out + (size_t)Bdim * Kdim * Cdim;       // (B,K,N)

    char* ws = (char*)d_ws;
    float* wArr  = (float*)(ws);                                 // 131072 B
    int*   kArr  = (int*)  (ws + 131072);                        // 131072 B
    int*   cnt   = (int*)  (ws + 262144);                        // 8192 B
    float* invc  = (float*)(ws + 270336);                        // 8192 B
    short* centH = (short*)(ws + 278528);                        // 3145728 B
    short* centM = (short*)(ws + 278528 + 3145728);              // 3145728 B
    short* centL = (short*)(ws + 278528 + 2 * 3145728);          // 3145728 B

    hipMemsetAsync(simOut, 0, (size_t)Bdim * Kdim * Ndim * sizeof(float), stream);

    prep_kernel<<<dim3(Bdim), dim3(256), 0, stream>>>(cents, invc, cnt);
    cvt_kernel<<<dim3(Bdim * 96), dim3(256), 0, stream>>>(cents, centH, centM, centL);
    sim_mfma_kernel<<<dim3(Bdim * (Ndim / NT)), dim3(256), 0, stream>>>(
        x, centH, centM, centL, alpha, beta, invc, simOut, wArr, kArr, cnt);
    agg_kernel<<<dim3(Bdim * (Cdim / CB2)), dim3(256), 0, stream>>>(
        x, cents, wArr, kArr, cnt, hyp);
}

// Round 13
// 209.317 us; speedup vs baseline: 1.3164x; 1.3164x over previous
//
#include <hip/hip_runtime.h>
#include <cmath>

#define Bdim 8
#define Cdim 768
#define Kdim 256
#define Ndim 4096
#define NT 64      // tokens per block in kernel 1
#define KC2 32     // C-chunk per MFMA stage (3-buffered)
#define NCH (Cdim / KC2)   // 24
#define CB2 4      // c-rows per block in fallback agg
#define NCOPY 4    // replicated LDS accumulators in fallback agg

typedef __bf16 bf16x8 __attribute__((ext_vector_type(8)));
typedef short  s16x8  __attribute__((ext_vector_type(8)));
typedef float  f32x4  __attribute__((ext_vector_type(4)));
union U8 { s16x8 s; bf16x8 b; };

// direct global->LDS DMA, 16B per lane, wave-uniform LDS base
typedef __attribute__((address_space(1))) const unsigned int g_u32;
typedef __attribute__((address_space(3))) unsigned int l_u32;
__device__ __forceinline__ void gload16(const void* g, void* l) {
    __builtin_amdgcn_global_load_lds((g_u32*)g, (l_u32*)l, 16, 0, 0);
}

__device__ __forceinline__ unsigned short bf16_rne(float f) {
    unsigned u = __float_as_uint(f);
    unsigned r = u + 0x7FFFu + ((u >> 16) & 1u);
    return (unsigned short)(r >> 16);
}
__device__ __forceinline__ float bf2f(unsigned short h) {
    return __uint_as_float((unsigned)h << 16);
}

// fallback-path native LDS float atomic (see r11/r12 notes)
__device__ __forceinline__ void lds_fadd_nc(float* p, float v) {
    auto lp = (__attribute__((address_space(3))) float*)p;
    asm volatile("ds_add_f32 %0, %1"
                 :: "v"((unsigned)(unsigned long long)lp), "v"(v));
}

// three-level bf16 split, RNE at each level; v = h + m + l + eps, |eps| <= 2^-27 |v|
__device__ __forceinline__ void split3(float v, short& h, short& m, short& l) {
    unsigned u = __float_as_uint(v);
    unsigned th = u + 0x7FFFu + ((u >> 16) & 1u);
    h = (short)(th >> 16);
    float r1 = v - __uint_as_float(th & 0xFFFF0000u);      // exact
    unsigned u1 = __float_as_uint(r1);
    unsigned tm = u1 + 0x7FFFu + ((u1 >> 16) & 1u);
    m = (short)(tm >> 16);
    float r2 = r1 - __uint_as_float(tm & 0xFFFF0000u);     // exact
    unsigned u2 = __float_as_uint(r2);
    unsigned tl = u2 + 0x7FFFu + ((u2 >> 16) & 1u);
    l = (short)(tl >> 16);
}

// Prep: per batch b — centroid inverse norms (fp32, exact) + zero cnt.
__global__ __launch_bounds__(256) void prep_kernel(
    const float* __restrict__ cents, float* __restrict__ invc, int* __restrict__ cnt)
{
    __shared__ float red[4][Kdim];
    const int tid = threadIdx.x;
    const int b = blockIdx.x;
    const float* cb = cents + (size_t)b * Cdim * Kdim;
    const int q = tid & 63, g = tid >> 6;
    float4 ss = make_float4(0.f, 0.f, 0.f, 0.f);
    for (int r = g; r < Cdim; r += 4) {
        float4 v = *(const float4*)(cb + (size_t)r * Kdim + q * 4);
        ss.x = fmaf(v.x, v.x, ss.x); ss.y = fmaf(v.y, v.y, ss.y);
        ss.z = fmaf(v.z, v.z, ss.z); ss.w = fmaf(v.w, v.w, ss.w);
    }
    *(float4*)&red[g][q * 4] = ss;
    __syncthreads();
    float s = red[0][tid] + red[1][tid] + red[2][tid] + red[3][tid];
    invc[b * Kdim + tid] = 1.f / fmaxf(sqrtf(s), 1e-12f);
    cnt[b * Kdim + tid] = 0;
}

// Cvt: centroids -> split-3 bf16 planes in MFMA-fragment layout
__global__ __launch_bounds__(256) void cvt_kernel(
    const float* __restrict__ cents, short* __restrict__ centH,
    short* __restrict__ centM, short* __restrict__ centL)
{
    const int k = threadIdx.x;
    const int bc = blockIdx.x;                    // b*96 + c8
    const float* src = cents + ((size_t)(bc / 96) * Cdim + (size_t)(bc % 96) * 8) * Kdim + k;
    s16x8 H, M, L;
    #pragma unroll
    for (int e = 0; e < 8; ++e) {
        short h, m, l;
        split3(src[(size_t)e * Kdim], h, m, l);
        H[e] = h; M[e] = m; L[e] = l;
    }
    ((s16x8*)centH)[(size_t)bc * 256 + k] = H;
    ((s16x8*)centM)[(size_t)bc * 256 + k] = M;
    ((s16x8*)centL)[(size_t)bc * 256 + k] = L;
}

// Transpose: x (B,C,N) f32 -> xTh (B,N,C) bf16.  64c x 64n LDS tiles.
__global__ __launch_bounds__(256) void xpose_kernel(
    const float* __restrict__ x, unsigned short* __restrict__ xTh)
{
    __shared__ float tile[64][68];      // +4 pad: 16B-aligned rows, broken banks
    const int tid = threadIdx.x;
    const int bid = blockIdx.x;
    const int b  = bid / (12 * 64);
    const int r  = bid % (12 * 64);
    const int ct = r / 64, nt = r % 64;
    const float* src = x + ((size_t)b * Cdim + ct * 64) * Ndim + nt * 64;
    #pragma unroll
    for (int it = 0; it < 4; ++it) {                // 1024 float4 loads
        int idx = tid + it * 256;
        int c = idx >> 4, n4 = idx & 15;
        float4 v = *(const float4*)&src[(size_t)c * Ndim + n4 * 4];
        *(float4*)&tile[c][n4 * 4] = v;
    }
    __syncthreads();
    #pragma unroll
    for (int it = 0; it < 8; ++it) {                // 2048 packed-u32 stores
        int idx = tid + it * 256;
        int n = idx >> 5, cp = idx & 31;
        unsigned pk = (unsigned)bf16_rne(tile[cp * 2][n])
                    | ((unsigned)bf16_rne(tile[cp * 2 + 1][n]) << 16);
        *(unsigned*)&xTh[((size_t)(b * Ndim + nt * 64 + n)) * Cdim + ct * 64 + cp * 2] = pk;
    }
}

// Scan: per batch — exclusive prefix over cnt, then bucket token ids.
__global__ __launch_bounds__(256) void scan_kernel(
    const int* __restrict__ cnt, const int* __restrict__ kArr,
    int* __restrict__ bucketOff, int* __restrict__ toks)
{
    __shared__ int cS[256];
    __shared__ int offS[256];
    __shared__ int cur[256];
    const int tid = threadIdx.x;
    const int b = blockIdx.x;
    cS[tid] = cnt[b * 256 + tid];
    __syncthreads();
    if (tid == 0) {
        int a = 0;
        for (int k = 0; k < 256; ++k) { offS[k] = a; a += cS[k]; }
    }
    __syncthreads();
    bucketOff[b * 256 + tid] = offS[tid];
    cur[tid] = offS[tid];
    __syncthreads();
    for (int i = tid; i < Ndim; i += 256) {
        int k = kArr[b * Ndim + i];
        int pos = atomicAdd(&cur[k], 1);            // native LDS int atomic
        toks[b * Ndim + pos] = i;
    }
}

// AggB: per (b, 2 k-buckets): 192 threads own 4 c each; gather bucket
// tokens' xT rows (coalesced 8B/lane), accumulate in registers, fused
// (acc + ct)/(cnt+1) epilogue.  No atomics, no LDS.
__global__ __launch_bounds__(192) void aggB_kernel(
    const unsigned short* __restrict__ xTh,
    const float* __restrict__ cents,
    const float* __restrict__ wArr,
    const int* __restrict__ toks,
    const int* __restrict__ bucketOff,
    const int* __restrict__ cnt,
    float* __restrict__ hyp)
{
    const int tid = threadIdx.x;          // 0..191
    const int b  = blockIdx.x >> 7;       // grid = 8*128
    const int kg = blockIdx.x & 127;
    const int t4 = tid * 4;
    #pragma unroll
    for (int j = 0; j < 2; ++j) {
        const int k = kg * 2 + j;
        const int off = bucketOff[b * 256 + k];
        const int num = cnt[b * 256 + k];
        const int base = b * Ndim + off;
        float a0 = 0.f, a1 = 0.f, a2 = 0.f, a3 = 0.f;
        int i = 0;
        for (; i + 4 <= num; i += 4) {    // 4 independent gathers in flight
            int na = toks[base + i],     nb = toks[base + i + 1];
            int nc = toks[base + i + 2], nd = toks[base + i + 3];
            float wa = wArr[b * Ndim + na], wb = wArr[b * Ndim + nb];
            float wc = wArr[b * Ndim + nc], wd = wArr[b * Ndim + nd];
            ushort4 ha = *(const ushort4*)&xTh[((size_t)(b * Ndim + na)) * Cdim + t4];
            ushort4 hb = *(const ushort4*)&xTh[((size_t)(b * Ndim + nb)) * Cdim + t4];
            ushort4 hc = *(const ushort4*)&xTh[((size_t)(b * Ndim + nc)) * Cdim + t4];
            ushort4 hd = *(const ushort4*)&xTh[((size_t)(b * Ndim + nd)) * Cdim + t4];
            a0 += wa * bf2f(ha.x) + wb * bf2f(hb.x) + wc * bf2f(hc.x) + wd * bf2f(hd.x);
            a1 += wa * bf2f(ha.y) + wb * bf2f(hb.y) + wc * bf2f(hc.y) + wd * bf2f(hd.y);
            a2 += wa * bf2f(ha.z) + wb * bf2f(hb.z) + wc * bf2f(hc.z) + wd * bf2f(hd.z);
            a3 += wa * bf2f(ha.w) + wb * bf2f(hb.w) + wc * bf2f(hc.w) + wd * bf2f(hd.w);
        }
        for (; i < num; ++i) {
            int n = toks[base + i];
            float w = wArr[b * Ndim + n];
            ushort4 h = *(const ushort4*)&xTh[((size_t)(b * Ndim + n)) * Cdim + t4];
            a0 += w * bf2f(h.x); a1 += w * bf2f(h.y);
            a2 += w * bf2f(h.z); a3 += w * bf2f(h.w);
        }
        float d = (float)(num + 1);
        float4 o;
        o.x = (a0 + cents[((size_t)b * Cdim + t4 + 0) * Kdim + k]) / d;
        o.y = (a1 + cents[((size_t)b * Cdim + t4 + 1) * Kdim + k]) / d;
        o.z = (a2 + cents[((size_t)b * Cdim + t4 + 2) * Kdim + k]) / d;
        o.w = (a3 + cents[((size_t)b * Cdim + t4 + 3) * Kdim + k]) / d;
        *(float4*)&hyp[((size_t)(b * Kdim + k)) * Cdim + t4] = o;
    }
}

// Kernel 1: cos via split-3 bf16 MFMA, 6 passes.  (unchanged since r8)
__global__ __launch_bounds__(256, 2) void sim_mfma_kernel(
    const float* __restrict__ x,
    const short* __restrict__ centH,
    const short* __restrict__ centM,
    const short* __restrict__ centL,
    const float* __restrict__ alpha_p,
    const float* __restrict__ beta_p,
    const float* __restrict__ invc,
    float* __restrict__ simOut,
    float* __restrict__ wArr,
    int*   __restrict__ kArr,
    int*   __restrict__ cnt)
{
    __shared__ __align__(16) float sxf[3][KC2][NT];
    __shared__ float invcS[Kdim];
    __shared__ float px[4][NT];
    __shared__ float invxS[NT];
    __shared__ float bwv[4][NT];
    __shared__ int   bwk[4][NT];

    const int tid  = threadIdx.x;
    const int lane = tid & 63;
    const int w    = tid >> 6;
    const int q    = lane >> 4;
    const int c15  = lane & 15;
    const int b    = blockIdx.x >> 6;
    const int n0   = (blockIdx.x & 63) * NT;
    const float* xb = x + (size_t)b * Cdim * Ndim;

    invcS[tid] = invc[b * Kdim + tid];
    const float alpha = alpha_p[0];
    const float beta  = beta_p[0];

    f32x4 acc[4][4];
    #pragma unroll
    for (int i = 0; i < 4; ++i)
        #pragma unroll
        for (int j = 0; j < 4; ++j) acc[i][j] = (f32x4){0.f, 0.f, 0.f, 0.f};

    float xn2p = 0.f;

    #define STAGE(t_) do {                                                    \
        const int bf_ = (t_) % 3; const int c0_ = (t_) * KC2;                 \
        _Pragma("unroll")                                                     \
        for (int i_ = 0; i_ < 2; ++i_)                                        \
            gload16(xb + (size_t)(c0_ + w * 8 + i_ * 4 + q) * Ndim            \
                       + n0 + c15 * 4,                                        \
                    &sxf[bf_][w * 8 + i_ * 4][0]);                            \
    } while (0)

    STAGE(0);
    STAGE(1);

    const s16x8* cHb = (const s16x8*)centH + ((size_t)b * 96) * 256;
    const s16x8* cMb = (const s16x8*)centM + ((size_t)b * 96) * 256;
    const s16x8* cLb = (const s16x8*)centL + ((size_t)b * 96) * 256;

    for (int t = 0; t < NCH; ++t) {
        asm volatile("s_waitcnt vmcnt(2)" ::: "memory");
        __builtin_amdgcn_s_barrier();
        __builtin_amdgcn_sched_barrier(0);

        const int cur = t % 3;

        U8 aH[4], aM[4], aL[4];
        {
            const size_t rowb = ((size_t)(t * 4 + q)) * 256 + w * 64 + c15;
            #pragma unroll
            for (int kf = 0; kf < 4; ++kf) {
                aH[kf].s = cHb[rowb + kf * 16];
                aM[kf].s = cMb[rowb + kf * 16];
                aL[kf].s = cLb[rowb + kf * 16];
            }
        }
        if (t + 2 < NCH) STAGE(t + 2);

        #pragma unroll
        for (int r = 0; r < 8; ++r) {
            float v = sxf[cur][w * 8 + r][lane];
            xn2p = fmaf(v, v, xn2p);
        }

        U8 bH[4], bM[4], bL[4];
        #pragma unroll
        for (int nf = 0; nf < 4; ++nf) {
            #pragma unroll
            for (int e = 0; e < 8; ++e) {
                short h, m, l;
                split3(sxf[cur][q * 8 + e][nf * 16 + c15], h, m, l);
                bH[nf].s[e] = h; bM[nf].s[e] = m; bL[nf].s[e] = l;
            }
        }

        #pragma unroll
        for (int kf = 0; kf < 4; ++kf)
            #pragma unroll
            for (int nf = 0; nf < 4; ++nf)
                acc[kf][nf] = __builtin_amdgcn_mfma_f32_16x16x32_bf16(
                    aH[kf].b, bH[nf].b, acc[kf][nf], 0, 0, 0);
        #pragma unroll
        for (int kf = 0; kf < 4; ++kf)
            #pragma unroll
            for (int nf = 0; nf < 4; ++nf)
                acc[kf][nf] = __builtin_amdgcn_mfma_f32_16x16x32_bf16(
                    aH[kf].b, bM[nf].b, acc[kf][nf], 0, 0, 0);
        #pragma unroll
        for (int kf = 0; kf < 4; ++kf)
            #pragma unroll
            for (int nf = 0; nf < 4; ++nf)
                acc[kf][nf] = __builtin_amdgcn_mfma_f32_16x16x32_bf16(
                    aM[kf].b, bH[nf].b, acc[kf][nf], 0, 0, 0);
        #pragma unroll
        for (int kf = 0; kf < 4; ++kf)
            #pragma unroll
            for (int nf = 0; nf < 4; ++nf)
                acc[kf][nf] = __builtin_amdgcn_mfma_f32_16x16x32_bf16(
                    aH[kf].b, bL[nf].b, acc[kf][nf], 0, 0, 0);
        #pragma unroll
        for (int kf = 0; kf < 4; ++kf)
            #pragma unroll
            for (int nf = 0; nf < 4; ++nf)
                acc[kf][nf] = __builtin_amdgcn_mfma_f32_16x16x32_bf16(
                    aL[kf].b, bH[nf].b, acc[kf][nf], 0, 0, 0);
        #pragma unroll
        for (int kf = 0; kf < 4; ++kf)
            #pragma unroll
            for (int nf = 0; nf < 4; ++nf)
                acc[kf][nf] = __builtin_amdgcn_mfma_f32_16x16x32_bf16(
                    aM[kf].b, bM[nf].b, acc[kf][nf], 0, 0, 0);
    }
    #undef STAGE

    __syncthreads();
    px[w][lane] = xn2p;
    __syncthreads();
    if (tid < NT) {
        float s = px[0][tid] + px[1][tid] + px[2][tid] + px[3][tid];
        invxS[tid] = 1.f / fmaxf(sqrtf(s), 1e-12f);
    }
    __syncthreads();

    #pragma unroll
    for (int nf = 0; nf < 4; ++nf) {
        const float ivx = invxS[nf * 16 + c15];
        float best = -1.f; int bk = 0;
        #pragma unroll
        for (int kf = 0; kf < 4; ++kf) {
            float4 ic = *(const float4*)&invcS[w * 64 + kf * 16 + q * 4];
            #pragma unroll
            for (int r = 0; r < 4; ++r) {
                float cosv = acc[kf][nf][r] * ((const float*)&ic)[r] * ivx;
                float s = 1.f / (1.f + expf(-(beta + alpha * cosv)));
                int k = w * 64 + kf * 16 + q * 4 + r;
                if (s > best) { best = s; bk = k; }
            }
        }
        #pragma unroll
        for (int off = 16; off < 64; off <<= 1) {
            float ov = __shfl_xor(best, off);
            int   ok = __shfl_xor(bk, off);
            if (ov > best || (ov == best && ok < bk)) { best = ov; bk = ok; }
        }
        if (q == 0) { bwv[w][nf * 16 + c15] = best; bwk[w][nf * 16 + c15] = bk; }
    }
    __syncthreads();
    if (tid < NT) {
        float best = -1.f; int bk = 0;
        #pragma unroll
        for (int g = 0; g < 4; ++g) {
            float v = bwv[g][tid];
            if (v > best) { best = v; bk = bwk[g][tid]; }
        }
        int gn = b * Ndim + n0 + tid;
        wArr[gn] = best;
        kArr[gn] = bk;
        simOut[((size_t)(b * Kdim + bk)) * Ndim + n0 + tid] = best;
        atomicAdd(&cnt[b * Kdim + bk], 1);
    }
}

// Fallback agg (r12) — used only when ws_size is too small for the new path.
__global__ __launch_bounds__(256, 4) void agg_kernel(
    const float* __restrict__ x, const float* __restrict__ cents,
    const float* __restrict__ wArr, const int* __restrict__ kArr,
    const int* __restrict__ cnt, float* __restrict__ hyp)
{
    __shared__ float accs[NCOPY][CB2][Kdim + 1];
    const int tid = threadIdx.x;
    const int b  = blockIdx.x / (Cdim / CB2);
    const int c0 = (blockIdx.x % (Cdim / CB2)) * CB2;
    const int cp = tid & 3;
    const float* xb = x + ((size_t)b * Cdim + c0) * Ndim;

    int4 kv[4]; float4 w4[4]; float4 xv[4][CB2];
    #pragma unroll
    for (int i = 0; i < 4; ++i) {
        const int n = (tid + i * 256) * 4;
        kv[i] = *(const int4*)&kArr[b * Ndim + n];
        w4[i] = *(const float4*)&wArr[b * Ndim + n];
        #pragma unroll
        for (int r = 0; r < CB2; ++r)
            xv[i][r] = *(const float4*)&xb[(size_t)r * Ndim + n];
    }
    for (int i = tid; i < NCOPY * CB2 * (Kdim + 1); i += 256) ((float*)accs)[i] = 0.f;
    __syncthreads();
    __builtin_amdgcn_sched_barrier(0);
    #pragma unroll
    for (int i = 0; i < 4; ++i)
        #pragma unroll
        for (int r = 0; r < CB2; ++r) {
            lds_fadd_nc(&accs[cp][r][kv[i].x], w4[i].x * xv[i][r].x);
            lds_fadd_nc(&accs[cp][r][kv[i].y], w4[i].y * xv[i][r].y);
            lds_fadd_nc(&accs[cp][r][kv[i].z], w4[i].z * xv[i][r].z);
            lds_fadd_nc(&accs[cp][r][kv[i].w], w4[i].w * xv[i][r].w);
        }
    asm volatile("s_waitcnt lgkmcnt(0)" ::: "memory");
    __builtin_amdgcn_sched_barrier(0);
    __syncthreads();
    const int cl = tid & 3;
    #pragma unroll
    for (int it = 0; it < 4; ++it) {
        int k = (tid >> 2) + it * 64;
        float s = accs[0][cl][k] + accs[1][cl][k] + accs[2][cl][k] + accs[3][cl][k];
        float num = s + cents[((size_t)b * Cdim + c0 + cl) * Kdim + k];
        hyp[((size_t)(b * Kdim + k)) * Cdim + c0 + cl] = num / (float)(cnt[b * Kdim + k] + 1);
    }
}

extern "C" void kernel_launch(void* const* d_in, const int* in_sizes, int n_in,
                              void* d_out, int out_size, void* d_ws, size_t ws_size,
                              hipStream_t stream)
{
    const float* x     = (const float*)d_in[0];
    const float* cents = (const float*)d_in[1];
    const float* alpha = (const float*)d_in[2];
    const float* beta  = (const float*)d_in[3];

    float* hyp    = (float*)d_out;                                    // (B,K,C)
    float* simOut = (float*)d_out + (size_t)Bdim * Kdim * Cdim;       // (B,K,N)

    char* ws = (char*)d_ws;
    float* wArr  = (float*)(ws);                                 // @0        131072
    int*   kArr  = (int*)  (ws + 131072);                        //           131072
    int*   cnt   = (int*)  (ws + 262144);                        //           8192
    float* invc  = (float*)(ws + 270336);                        //           8192
    short* centH = (short*)(ws + 278528);                        //           3145728
    short* centM = (short*)(ws + 3424256);                       //           3145728
    short* centL = (short*)(ws + 6569984);                       //           3145728
    int*   toks  = (int*)  (ws + 9715712);                       //           131072
    int*   boff  = (int*)  (ws + 9846784);                       //           8192
    unsigned short* xTh = (unsigned short*)(ws + 9854976);       //           50331648
    const size_t WS_NEED = 9854976ull + 50331648ull;             // 60,186,624

    hipMemsetAsync(simOut, 0, (size_t)Bdim * Kdim * Ndim * sizeof(float), stream);

    prep_kernel<<<dim3(Bdim), dim3(256), 0, stream>>>(cents, invc, cnt);
    cvt_kernel<<<dim3(Bdim * 96), dim3(256), 0, stream>>>(cents, centH, centM, centL);

    if (ws_size >= WS_NEED) {
        xpose_kernel<<<dim3(Bdim * 12 * 64), dim3(256), 0, stream>>>(x, xTh);
        sim_mfma_kernel<<<dim3(Bdim * (Ndim / NT)), dim3(256), 0, stream>>>(
            x, centH, centM, centL, alpha, beta, invc, simOut, wArr, kArr, cnt);
        scan_kernel<<<dim3(Bdim), dim3(256), 0, stream>>>(cnt, kArr, boff, toks);
        aggB_kernel<<<dim3(Bdim * 128), dim3(192), 0, stream>>>(
            xTh, cents, wArr, toks, boff, cnt, hyp);
    } else {
        sim_mfma_kernel<<<dim3(Bdim * (Ndim / NT)), dim3(256), 0, stream>>>(
            x, centH, centM, centL, alpha, beta, invc, simOut, wArr, kArr, cnt);
        agg_kernel<<<dim3(Bdim * (Cdim / CB2)), dim3(256), 0, stream>>>(
            x, cents, wArr, kArr, cnt, hyp);
    }
}